// Round 14
// baseline (505.874 us; speedup 1.0000x reference)
//
#include <hip/hip_runtime.h>
#include <hip/hip_bf16.h>

typedef __attribute__((ext_vector_type(8))) short bf16x8;
typedef __attribute__((ext_vector_type(4))) short bf16x4;
typedef __attribute__((ext_vector_type(4))) float f32x4;
typedef unsigned short ushort_t;
typedef unsigned int uint_t;

__device__ __forceinline__ f32x4 mfma32(bf16x8 a, bf16x8 b, f32x4 c) {
    return __builtin_amdgcn_mfma_f32_16x16x32_bf16(a, b, c, 0, 0, 0);
}
#if __has_builtin(__builtin_amdgcn_mfma_f32_16x16x16bf16_1k)
#define HAVE_MFMA16 1
__device__ __forceinline__ f32x4 mfma16(bf16x4 a, bf16x4 b, f32x4 c) {
    return __builtin_amdgcn_mfma_f32_16x16x16bf16_1k(a, b, c, 0, 0, 0);
}
#else
#define HAVE_MFMA16 0
#endif

namespace {
constexpr int Bn = 4;
constexpr int Nn = 8192;
constexpr float SCALEf = 0.17677669529663687f; // 32^-0.5
constexpr float EPSf = 1e-5f;

// d_ws byte offsets
constexpr size_t WS_QW  = 0;        // 256*256*2
constexpr size_t WS_PW  = 131072;
constexpr size_t WS_KW0 = 262144;   // 256*128*2
constexpr size_t WS_KW1 = 327680;
constexpr size_t WS_CW0 = 393216;   // 128*64*2
constexpr size_t WS_CW1 = 409600;   // 128*128*2
constexpr size_t WS_CB0 = 442368;   // 128*4 f32
constexpr size_t WS_CB1 = 442880;
constexpr size_t WS_AO  = 458752;   // ao [4][8192][256] bf16 = 16.8MB
}

__device__ __forceinline__ uint_t f2b(float f) {
    union { float f; uint_t u; } v; v.f = f;
    return (v.u + 0x7fffu + ((v.u >> 16) & 1u)) >> 16;   // RNE
}
__device__ __forceinline__ float b2f(ushort_t u) {
    union { uint_t u; float f; } v; v.u = ((uint_t)u) << 16;
    return v.f;
}
// packed f32x2 -> bf16x2 via compiler (emits v_cvt_pk_bf16_f32; RNE)
__device__ __forceinline__ uint_t pk2(float lo, float hi) {
    __hip_bfloat162 h = __float22bfloat162_rn(float2{lo, hi});
    union { __hip_bfloat162 h; uint_t u; } v; v.h = h;
    return v.u;
}

template<int KC>
__device__ __forceinline__ int swz(int r, int c) {
    constexpr int SW = (KC / 8 < 16 ? KC / 8 : 16);
    return r * KC + ((((c >> 3) ^ (r & (SW - 1))) << 3) | (c & 7));
}

// -------- prep: f32 weights -> bf16 (+ BN fold) --------
__global__ void plsa_prep(const float* __restrict__ qw,
                          const float* __restrict__ c0w, const float* __restrict__ g0,
                          const float* __restrict__ b0,  const float* __restrict__ m0,
                          const float* __restrict__ v0,  const float* __restrict__ k0w,
                          const float* __restrict__ c1w, const float* __restrict__ g1,
                          const float* __restrict__ b1,  const float* __restrict__ m1,
                          const float* __restrict__ v1,  const float* __restrict__ k1w,
                          const float* __restrict__ pw,  char* ws) {
    const int i = blockIdx.x * 256 + threadIdx.x;   // 0 .. 65535
    ((ushort_t*)(ws + WS_QW))[i] = (ushort_t)f2b(qw[i]);
    ((ushort_t*)(ws + WS_PW))[i] = (ushort_t)f2b(pw[i]);
    if (i < 32768) {
        ((ushort_t*)(ws + WS_KW0))[i] = (ushort_t)f2b(k0w[i]);
        ((ushort_t*)(ws + WS_KW1))[i] = (ushort_t)f2b(k1w[i]);
    }
    if (i < 8192)  { int o = i >> 6;  float inv = g0[o] * rsqrtf(v0[o] + EPSf);
                     ((ushort_t*)(ws + WS_CW0))[i] = (ushort_t)f2b(c0w[i] * inv); }
    if (i < 16384) { int o = i >> 7;  float inv = g1[o] * rsqrtf(v1[o] + EPSf);
                     ((ushort_t*)(ws + WS_CW1))[i] = (ushort_t)f2b(c1w[i] * inv); }
    if (i < 128) {
        float i0 = g0[i] * rsqrtf(v0[i] + EPSf);
        float i1 = g1[i] * rsqrtf(v1[i] + EPSf);
        ((float*)(ws + WS_CB0))[i] = b0[i] - m0[i] * i0;
        ((float*)(ws + WS_CB1))[i] = b1[i] - m1[i] * i1;
    }
}

// issue 4-pt chunk loads into registers: CIN/4 f32 per thread
template<int CIN>
__device__ __forceinline__ void issue_y4(const float* __restrict__ yb, int b, int n0c,
                                         float* yreg, int tid) {
    constexpr int ITER = CIN / 8;
    #pragma unroll
    for (int it = 0; it < ITER; ++it) {
        const int idx = tid + it * 256;
        const int pk = idx & 63, c0 = (idx >> 6) * 2;
        const float* ysrc = yb + ((size_t)(b * CIN + c0)) * (Nn * 16)
                               + (size_t)(n0c + (pk >> 4)) * 16 + (pk & 15);
        yreg[it * 2]     = ysrc[0];
        yreg[it * 2 + 1] = ysrc[(size_t)Nn * 16];
    }
}
template<int CIN>
__device__ __forceinline__ void write_y4(ushort_t* Ys, const float* yreg, int tid) {
    constexpr int ITER = CIN / 8;
    #pragma unroll
    for (int it = 0; it < ITER; ++it) {
        const int idx = tid + it * 256;
        const int pk = idx & 63, c0 = (idx >> 6) * 2;
        *(uint_t*)(Ys + swz<CIN>(pk, c0)) = pk2(yreg[it * 2], yreg[it * 2 + 1]);
    }
}

// -------- one scale branch: 4 chunks of 4 points, 2 barriers per chunk --------
// weights NOT hoisted (L1/L2-resident)
template<int CIN, int NCIN>
__device__ __forceinline__ void branch_run(
    int tid, int b, int n0,
    const float* __restrict__ yb, const float* __restrict__ ynext,
    const char* __restrict__ ws,
    ushort_t* Ys, ushort_t* Zs, ushort_t* Ks, ushort_t* Vs,
    const ushort_t* qs, ushort_t* aobuf, float* yreg)
{
    constexpr size_t wcw = (CIN == 64) ? WS_CW0 : WS_CW1;
    constexpr size_t wcb = (CIN == 64) ? WS_CB0 : WS_CB1;
    constexpr size_t wkw = (CIN == 64) ? WS_KW0 : WS_KW1;
    constexpr int qb = (CIN == 64) ? 0 : 128;
    constexpr int KT = CIN / 32;

    const ushort_t* cwb = (const ushort_t*)(ws + wcw);
    const float*    cbb = (const float*)(ws + wcb);
    const ushort_t* kwb = (const ushort_t*)(ws + wkw);
    const int w = tid >> 6, lane = tid & 63, l15 = lane & 15, lk = lane >> 4;

    #pragma unroll 1
    for (int cc = 0; cc < 4; ++cc) {
        // ---- phase A: issue next-chunk loads (register prefetch), conv GEMM ----
        if (cc < 3) issue_y4<CIN>(yb, b, n0 + (cc + 1) * 4, yreg, tid);
        else if constexpr (NCIN != 0) issue_y4<NCIN>(ynext, b, n0, yreg, tid);

        #pragma unroll
        for (int ct = 0; ct < 4; ++ct) {
            bf16x8 bfr[KT];
            #pragma unroll
            for (int k = 0; k < KT; ++k)
                bfr[k] = *(const bf16x8*)(Ys + swz<CIN>(ct * 16 + l15, k * 32 + lk * 8));
            #pragma unroll
            for (int mi = 0; mi < 2; ++mi) {
                f32x4 a = f32x4{0.f, 0.f, 0.f, 0.f};
                #pragma unroll
                for (int k = 0; k < KT; ++k) {
                    bf16x8 af = *(const bf16x8*)(cwb + ((w * 2 + mi) * 16 + l15) * CIN + k * 32 + lk * 8);
                    a = mfma32(af, bfr[k], a);
                }
                const int col = ct * 16 + l15, o0 = (w * 2 + mi) * 16 + lk * 4;
                const float4 cb4 = *(const float4*)(cbb + (w * 2 + mi) * 16 + lk * 4);
                const float z0 = fmaxf(a.x + cb4.x, 0.f);
                const float z1 = fmaxf(a.y + cb4.y, 0.f);
                const float z2 = fmaxf(a.z + cb4.z, 0.f);
                const float z3 = fmaxf(a.w + cb4.w, 0.f);
                const int off = swz<128>(col, o0);
                *(uint_t*)(Zs + off)     = pk2(z0, z1);
                *(uint_t*)(Zs + off + 2) = pk2(z2, z3);
            }
        }
        __syncthreads();

        // ---- phase B: kv GEMM -> Ks/Vs; LDS-write of prefetched y ----
        #pragma unroll
        for (int ct = 0; ct < 4; ++ct) {
            bf16x8 bfr[4];
            #pragma unroll
            for (int k = 0; k < 4; ++k)
                bfr[k] = *(const bf16x8*)(Zs + swz<128>(ct * 16 + l15, k * 32 + lk * 8));
            const int col = ct * 16 + l15;
            #pragma unroll
            for (int mi = 0; mi < 4; ++mi) {
                f32x4 a = f32x4{0.f, 0.f, 0.f, 0.f};
                #pragma unroll
                for (int k = 0; k < 4; ++k) {
                    bf16x8 af = *(const bf16x8*)(kwb + ((w * 4 + mi) * 16 + l15) * 128 + k * 32 + lk * 8);
                    a = mfma32(af, bfr[k], a);
                }
                const int j0 = (w * 4 + mi) * 16 + lk * 4;
                const int h = j0 >> 6;
                const int d0 = (j0 & 63) >> 1;   // even
                *(uint_t*)(Ks + swz<128>(col, h * 32 + d0)) = pk2(a.x, a.z);
                const uint_t vv = pk2(a.y, a.w);
                Vs[swz<64>(h * 32 + d0,     col)] = (ushort_t)vv;
                Vs[swz<64>(h * 32 + d0 + 1, col)] = (ushort_t)(vv >> 16);
            }
        }
        if (cc < 3) write_y4<CIN>(Ys, yreg, tid);
        else if constexpr (NCIN != 0) write_y4<NCIN>(Ys, yreg, tid);
        __syncthreads();

        // ---- phase C: MFMA logits + softmax + MFMA PV (wave = one point) ----
#if HAVE_MFMA16
        {
            const int pt = w;   // wave handles one point, all 4 heads
            #pragma unroll
            for (int h = 0; h < 4; ++h) {
                // QK^T: D[kk][*] = K[kk][d] x q[d]   (A row=kk=l15, k=d=lk*8+j)
                bf16x8 ka  = *(const bf16x8*)(Ks + swz<128>(pt * 16 + l15, h * 32 + lk * 8));
                bf16x8 qf  = *(const bf16x8*)(qs + swz<256>(cc * 4 + pt, qb + h * 32 + lk * 8));
                f32x4 zero = f32x4{0.f, 0.f, 0.f, 0.f};
                f32x4 sc = mfma32(ka, qf, zero);
                // lane holds S[kk = lk*4+reg] (cols duplicated across l15)
                float s0 = sc.x * SCALEf, s1 = sc.y * SCALEf;
                float s2 = sc.z * SCALEf, s3 = sc.w * SCALEf;
                float mx = fmaxf(fmaxf(s0, s1), fmaxf(s2, s3));
                mx = fmaxf(mx, __shfl_xor(mx, 16));
                mx = fmaxf(mx, __shfl_xor(mx, 32));
                float e0 = __expf(s0 - mx), e1 = __expf(s1 - mx);
                float e2 = __expf(s2 - mx), e3 = __expf(s3 - mx);
                float t = e0 + e1 + e2 + e3;
                t += __shfl_xor(t, 16);
                t += __shfl_xor(t, 32);
                const float r = 1.f / t;
                union { uint_t u[2]; bf16x4 v; } pf;
                pf.u[0] = pk2(e0 * r, e1 * r);
                pf.u[1] = pk2(e2 * r, e3 * r);
                // PV: D[d][*] = V[d][kk] x P[kk]  (A row=d=l15, k=kk=lk*4+j)
                #pragma unroll
                for (int dblk = 0; dblk < 2; ++dblk) {
                    bf16x4 va = *(const bf16x4*)(Vs + swz<64>(h * 32 + dblk * 16 + l15, pt * 16 + lk * 4));
                    f32x4 o = mfma16(va, pf.v, zero);
                    if (l15 == 0) {
                        uint2 ou;
                        ou.x = pk2(o.x, o.y);
                        ou.y = pk2(o.z, o.w);
                        *(uint2*)(aobuf + ((size_t)(b * Nn + n0 + cc * 4 + pt)) * 256
                                  + qb + h * 32 + dblk * 16 + lk * 4) = ou;
                    }
                }
            }
        }
#else
        {
            const int pt = w;
            #pragma unroll
            for (int hp = 0; hp < 2; ++hp) {
                float p = 0.f;
                if (lane < 32) {
                    const int kk = lane & 15;
                    const int h = hp * 2 + (lane >> 4);
                    float s = 0.f;
                    #pragma unroll
                    for (int dc = 0; dc < 4; ++dc) {
                        bf16x8 q8 = *(const bf16x8*)(qs + swz<256>(cc * 4 + pt, qb + h * 32 + dc * 8));
                        bf16x8 k8 = *(const bf16x8*)(Ks + swz<128>(pt * 16 + kk, h * 32 + dc * 8));
                        #pragma unroll
                        for (int j = 0; j < 8; ++j)
                            s += b2f((ushort_t)q8[j]) * b2f((ushort_t)k8[j]);
                    }
                    s *= SCALEf;
                    float mx = s;
                    #pragma unroll
                    for (int m = 1; m < 16; m <<= 1) mx = fmaxf(mx, __shfl_xor(mx, m));
                    const float e = __expf(s - mx);
                    float sum = e;
                    #pragma unroll
                    for (int m = 1; m < 16; m <<= 1) sum += __shfl_xor(sum, m);
                    p = e / sum;
                }
                const int d = lane & 31, hh2 = lane >> 5;
                const int h2 = hp * 2 + hh2;
                const int row = h2 * 32 + d;
                bf16x8 va = *(const bf16x8*)(Vs + swz<64>(row, pt * 16));
                bf16x8 vb = *(const bf16x8*)(Vs + swz<64>(row, pt * 16 + 8));
                float o = 0.f;
                #pragma unroll
                for (int j = 0; j < 8; ++j) {
                    o += __shfl(p, hh2 * 16 + j)     * b2f((ushort_t)va[j]);
                    o += __shfl(p, hh2 * 16 + 8 + j) * b2f((ushort_t)vb[j]);
                }
                aobuf[((size_t)(b * Nn + n0 + cc * 4 + pt)) * 256 + qb + h2 * 32 + d] = (ushort_t)f2b(o);
            }
        }
#endif
    }
}

// -------- fused attention kernel: inline Q GEMM + both branches --------
__global__ __launch_bounds__(256, 2) void k_attn(
    const float* __restrict__ x, const float* __restrict__ y0, const float* __restrict__ y1,
    const char* __restrict__ ws, ushort_t* __restrict__ aobuf) {

    __shared__ __align__(16) ushort_t qs[4096];   // [16 pt][256 ch] swz
    __shared__ __align__(16) ushort_t Ys[8192];   // [64 col][CIN] (X overlay in prologue)
    __shared__ __align__(16) ushort_t Zs[8192];   // [64 col][128 o]
    __shared__ __align__(16) ushort_t Ks[8192];   // [64 col][128 hd]
    __shared__ __align__(16) ushort_t Vs[8192];   // [128 hd][64 col]

    const int tid = threadIdx.x;
    const int b = blockIdx.x >> 9, n0 = (blockIdx.x & 511) << 4;
    const int w = tid >> 6, lane = tid & 63, l15 = lane & 15, lk = lane >> 4;
    float yreg[32];

    // ---- prologue: stage x in two 8-reg halves (cuts peak pressure) ----
    const int xn = tid & 15, cg = tid >> 4;
    #pragma unroll
    for (int hseg = 0; hseg < 2; ++hseg) {
        float xreg[8];
        #pragma unroll
        for (int i = 0; i < 8; ++i)
            xreg[i] = x[((size_t)(b * 256 + cg * 16 + hseg * 8 + i)) * Nn + n0 + xn];
        #pragma unroll
        for (int j = 0; j < 4; ++j)
            *(uint_t*)(Ys + swz<256>(xn, cg * 16 + hseg * 8 + 2 * j)) =
                pk2(xreg[2 * j], xreg[2 * j + 1]);
    }
    issue_y4<64>(y0, b, n0, yreg, tid);
    __syncthreads();

    // ---- Q GEMM: qs[pt][ch] = QW[ch][c] * X[c][pt] ----
    {
        const ushort_t* qwb = (const ushort_t*)(ws + WS_QW);
        #pragma unroll
        for (int mi = 0; mi < 4; ++mi) {
            f32x4 acc = f32x4{0.f, 0.f, 0.f, 0.f};
            #pragma unroll
            for (int k = 0; k < 8; ++k) {
                bf16x8 af = *(const bf16x8*)(qwb + ((w * 4 + mi) * 16 + l15) * 256 + k * 32 + lk * 8);
                bf16x8 bf = *(const bf16x8*)(Ys + swz<256>(l15, k * 32 + lk * 8));
                acc = mfma32(af, bf, acc);
            }
            const int ch0 = (w * 4 + mi) * 16 + lk * 4;
            uint2 u;
            u.x = pk2(acc.x, acc.y);
            u.y = pk2(acc.z, acc.w);
            *(uint2*)(qs + swz<256>(l15, ch0)) = u;
        }
    }
    __syncthreads();

    write_y4<64>(Ys, yreg, tid);   // X dead; stage branch0 chunk0
    __syncthreads();

    branch_run<64, 128>(tid, b, n0, y0, y1, ws, Ys, Zs, Ks, Vs, qs, aobuf, yreg);
    branch_run<128, 0> (tid, b, n0, y1, nullptr, ws, Ys, Zs, Ks, Vs, qs, aobuf, yreg);
}

// -------- proj GEMM + bias -> out[b][co][n] f32 --------
__global__ __launch_bounds__(256, 2) void k_proj(const char* __restrict__ ws,
                                                 const float* __restrict__ proj_b,
                                                 float* __restrict__ out) {
    __shared__ __align__(16) ushort_t At[64 * 256];
    const ushort_t* pwb = (const ushort_t*)(ws + WS_PW);
    const ushort_t* aobuf = (const ushort_t*)(ws + WS_AO);
    const int tid = threadIdx.x;
    const int b = blockIdx.x >> 7, n0 = (blockIdx.x & 127) * 64;

    {   // stage ao[n][ch] -> At[n][c] (bf16 pairs)
        const int cp = tid & 127, ng = tid >> 7;
        #pragma unroll
        for (int i = 0; i < 32; ++i) {
            const int n = ng + i * 2;
            const uint_t u = *(const uint_t*)(aobuf + ((size_t)(b * Nn + n0 + n)) * 256 + cp * 2);
            *(uint_t*)(At + swz<256>(n, cp * 2)) = u;
        }
    }
    __syncthreads();

    const int w = tid >> 6, lane = tid & 63, l15 = lane & 15, lk = lane >> 4;
    #pragma unroll
    for (int mi = 0; mi < 4; ++mi) {
        bf16x8 af[8];
        #pragma unroll
        for (int k = 0; k < 8; ++k)
            af[k] = *(const bf16x8*)(pwb + (w * 64 + mi * 16 + l15) * 256 + k * 32 + lk * 8);
        const int ch0 = w * 64 + mi * 16 + lk * 4;
        const float4 pbv = *(const float4*)(proj_b + ch0);
        #pragma unroll
        for (int ct = 0; ct < 4; ++ct) {
            f32x4 acc = f32x4{0.f, 0.f, 0.f, 0.f};
            #pragma unroll
            for (int k = 0; k < 8; ++k) {
                bf16x8 bf = *(const bf16x8*)(At + swz<256>(ct * 16 + l15, k * 32 + lk * 8));
                acc = mfma32(af[k], bf, acc);
            }
            const int nn = n0 + ct * 16 + l15;
            out[((size_t)(b * 256 + ch0 + 0)) * Nn + nn] = acc.x + pbv.x;
            out[((size_t)(b * 256 + ch0 + 1)) * Nn + nn] = acc.y + pbv.y;
            out[((size_t)(b * 256 + ch0 + 2)) * Nn + nn] = acc.z + pbv.z;
            out[((size_t)(b * 256 + ch0 + 3)) * Nn + nn] = acc.w + pbv.w;
        }
    }
}

extern "C" void kernel_launch(void* const* d_in, const int* in_sizes, int n_in,
                              void* d_out, int out_size, void* d_ws, size_t ws_size,
                              hipStream_t stream) {
    const float* x       = (const float*)d_in[0];
    const float* y0      = (const float*)d_in[1];
    const float* y1      = (const float*)d_in[2];
    const float* q_w     = (const float*)d_in[3];
    const float* conv0_w = (const float*)d_in[4];
    const float* bn0_g   = (const float*)d_in[5];
    const float* bn0_b   = (const float*)d_in[6];
    const float* bn0_m   = (const float*)d_in[7];
    const float* bn0_v   = (const float*)d_in[8];
    const float* kv0_w   = (const float*)d_in[9];
    const float* conv1_w = (const float*)d_in[10];
    const float* bn1_g   = (const float*)d_in[11];
    const float* bn1_b   = (const float*)d_in[12];
    const float* bn1_m   = (const float*)d_in[13];
    const float* bn1_v   = (const float*)d_in[14];
    const float* kv1_w   = (const float*)d_in[15];
    const float* proj_w  = (const float*)d_in[16];
    const float* proj_b  = (const float*)d_in[17];
    char* ws = (char*)d_ws;

    plsa_prep<<<256, 256, 0, stream>>>(q_w, conv0_w, bn0_g, bn0_b, bn0_m, bn0_v, kv0_w,
                                       conv1_w, bn1_g, bn1_b, bn1_m, bn1_v, kv1_w,
                                       proj_w, ws);
    k_attn<<<Bn * (Nn / 16), 256, 0, stream>>>(x, y0, y1, ws,
                                               (ushort_t*)(ws + WS_AO));
    k_proj<<<Bn * (Nn / 64), 256, 0, stream>>>(ws, proj_b, (float*)d_out);
}

// Round 15
// 248.288 us; speedup vs baseline: 2.0375x; 2.0375x over previous
//
#include <hip/hip_runtime.h>
#include <hip/hip_bf16.h>

typedef __attribute__((ext_vector_type(8))) short bf16x8;
typedef __attribute__((ext_vector_type(4))) short bf16x4;
typedef __attribute__((ext_vector_type(4))) float f32x4;
typedef unsigned short ushort_t;
typedef unsigned int uint_t;

__device__ __forceinline__ f32x4 mfma32(bf16x8 a, bf16x8 b, f32x4 c) {
    return __builtin_amdgcn_mfma_f32_16x16x32_bf16(a, b, c, 0, 0, 0);
}
#if __has_builtin(__builtin_amdgcn_mfma_f32_16x16x16bf16_1k)
#define HAVE_MFMA16 1
__device__ __forceinline__ f32x4 mfma16(bf16x4 a, bf16x4 b, f32x4 c) {
    return __builtin_amdgcn_mfma_f32_16x16x16bf16_1k(a, b, c, 0, 0, 0);
}
#else
#define HAVE_MFMA16 0
#endif

namespace {
constexpr int Bn = 4;
constexpr int Nn = 8192;
constexpr float SCALEf = 0.17677669529663687f; // 32^-0.5
constexpr float EPSf = 1e-5f;

// d_ws byte offsets
constexpr size_t WS_QW  = 0;        // 256*256*2
constexpr size_t WS_PW  = 131072;
constexpr size_t WS_KW0 = 262144;   // 256*128*2
constexpr size_t WS_KW1 = 327680;
constexpr size_t WS_CW0 = 393216;   // 128*64*2
constexpr size_t WS_CW1 = 409600;   // 128*128*2
constexpr size_t WS_CB0 = 442368;   // 128*4 f32
constexpr size_t WS_CB1 = 442880;
constexpr size_t WS_AO  = 458752;   // ao [4][8192][256] bf16 = 16.8MB
}

__device__ __forceinline__ uint_t f2b(float f) {
    union { float f; uint_t u; } v; v.f = f;
    return (v.u + 0x7fffu + ((v.u >> 16) & 1u)) >> 16;   // RNE
}
__device__ __forceinline__ float b2f(ushort_t u) {
    union { uint_t u; float f; } v; v.u = ((uint_t)u) << 16;
    return v.f;
}
// packed f32x2 -> bf16x2 via compiler (emits v_cvt_pk_bf16_f32; RNE)
__device__ __forceinline__ uint_t pk2(float lo, float hi) {
    __hip_bfloat162 h = __float22bfloat162_rn(float2{lo, hi});
    union { __hip_bfloat162 h; uint_t u; } v; v.h = h;
    return v.u;
}

template<int KC>
__device__ __forceinline__ int swz(int r, int c) {
    constexpr int SW = (KC / 8 < 16 ? KC / 8 : 16);
    return r * KC + ((((c >> 3) ^ (r & (SW - 1))) << 3) | (c & 7));
}

// -------- prep: f32 weights -> bf16 (+ BN fold) --------
__global__ void plsa_prep(const float* __restrict__ qw,
                          const float* __restrict__ c0w, const float* __restrict__ g0,
                          const float* __restrict__ b0,  const float* __restrict__ m0,
                          const float* __restrict__ v0,  const float* __restrict__ k0w,
                          const float* __restrict__ c1w, const float* __restrict__ g1,
                          const float* __restrict__ b1,  const float* __restrict__ m1,
                          const float* __restrict__ v1,  const float* __restrict__ k1w,
                          const float* __restrict__ pw,  char* ws) {
    const int i = blockIdx.x * 256 + threadIdx.x;   // 0 .. 65535
    ((ushort_t*)(ws + WS_QW))[i] = (ushort_t)f2b(qw[i]);
    ((ushort_t*)(ws + WS_PW))[i] = (ushort_t)f2b(pw[i]);
    if (i < 32768) {
        ((ushort_t*)(ws + WS_KW0))[i] = (ushort_t)f2b(k0w[i]);
        ((ushort_t*)(ws + WS_KW1))[i] = (ushort_t)f2b(k1w[i]);
    }
    if (i < 8192)  { int o = i >> 6;  float inv = g0[o] * rsqrtf(v0[o] + EPSf);
                     ((ushort_t*)(ws + WS_CW0))[i] = (ushort_t)f2b(c0w[i] * inv); }
    if (i < 16384) { int o = i >> 7;  float inv = g1[o] * rsqrtf(v1[o] + EPSf);
                     ((ushort_t*)(ws + WS_CW1))[i] = (ushort_t)f2b(c1w[i] * inv); }
    if (i < 128) {
        float i0 = g0[i] * rsqrtf(v0[i] + EPSf);
        float i1 = g1[i] * rsqrtf(v1[i] + EPSf);
        ((float*)(ws + WS_CB0))[i] = b0[i] - m0[i] * i0;
        ((float*)(ws + WS_CB1))[i] = b1[i] - m1[i] * i1;
    }
}

// issue 2-pt chunk loads into registers: CIN/8 f32 per thread
template<int CIN>
__device__ __forceinline__ void issue_y2(const float* __restrict__ yb, int b, int n0c,
                                         float* yreg, int tid) {
    constexpr int ITER = CIN / 16;
    #pragma unroll
    for (int it = 0; it < ITER; ++it) {
        const int idx = tid + it * 256;
        const int pk = idx & 31, c0 = (idx >> 5) * 2;
        const float* ysrc = yb + ((size_t)(b * CIN + c0)) * (Nn * 16)
                               + (size_t)(n0c + (pk >> 4)) * 16 + (pk & 15);
        yreg[it * 2]     = ysrc[0];
        yreg[it * 2 + 1] = ysrc[(size_t)Nn * 16];
    }
}
template<int CIN>
__device__ __forceinline__ void write_y2(ushort_t* Ys, const float* yreg, int tid) {
    constexpr int ITER = CIN / 16;
    #pragma unroll
    for (int it = 0; it < ITER; ++it) {
        const int idx = tid + it * 256;
        const int pk = idx & 31, c0 = (idx >> 5) * 2;
        *(uint_t*)(Ys + swz<CIN>(pk, c0)) = pk2(yreg[it * 2], yreg[it * 2 + 1]);
    }
}

// -------- one scale branch: 8 chunks of 2 points, 2 barriers per chunk --------
// conv/kv weights HOISTED into registers (per-branch; fits 2-blocks/CU unified file)
template<int CIN, int NCIN>
__device__ __forceinline__ void branch_run(
    int tid, int b, int n0,
    const float* __restrict__ yb, const float* __restrict__ ynext,
    const char* __restrict__ ws,
    ushort_t* Ys, ushort_t* Zs, ushort_t* Ks, ushort_t* Vs,
    const ushort_t* qs, ushort_t* aobuf, float* yreg)
{
    constexpr size_t wcw = (CIN == 64) ? WS_CW0 : WS_CW1;
    constexpr size_t wcb = (CIN == 64) ? WS_CB0 : WS_CB1;
    constexpr size_t wkw = (CIN == 64) ? WS_KW0 : WS_KW1;
    constexpr int qb = (CIN == 64) ? 0 : 128;
    constexpr int KT = CIN / 32;

    const ushort_t* cwb = (const ushort_t*)(ws + wcw);
    const float*    cbb = (const float*)(ws + wcb);
    const ushort_t* kwb = (const ushort_t*)(ws + wkw);
    const int w = tid >> 6, lane = tid & 63, l15 = lane & 15, lk = lane >> 4;

    // hoist weights (read once per block per branch; live in unified VGPR/AGPR file)
    bf16x8 cwf[2 * KT]; float4 cbv[2];
    #pragma unroll
    for (int mi = 0; mi < 2; ++mi) {
        #pragma unroll
        for (int k = 0; k < KT; ++k)
            cwf[mi * KT + k] = *(const bf16x8*)(cwb + ((w * 2 + mi) * 16 + l15) * CIN + k * 32 + lk * 8);
        cbv[mi] = *(const float4*)(cbb + (w * 2 + mi) * 16 + lk * 4);
    }
    bf16x8 kwf[16];
    #pragma unroll
    for (int mi = 0; mi < 4; ++mi)
        #pragma unroll
        for (int k = 0; k < 4; ++k)
            kwf[mi * 4 + k] = *(const bf16x8*)(kwb + ((w * 4 + mi) * 16 + l15) * 128 + k * 32 + lk * 8);

    #pragma unroll 1
    for (int cc = 0; cc < 8; ++cc) {
        // ---- phase A: issue next-chunk loads (register prefetch), conv GEMM ----
        if (cc < 7) issue_y2<CIN>(yb, b, n0 + (cc + 1) * 2, yreg, tid);
        else if constexpr (NCIN != 0) issue_y2<NCIN>(ynext, b, n0, yreg, tid);

        #pragma unroll
        for (int ct = 0; ct < 2; ++ct) {
            bf16x8 bfr[KT];
            #pragma unroll
            for (int k = 0; k < KT; ++k)
                bfr[k] = *(const bf16x8*)(Ys + swz<CIN>(ct * 16 + l15, k * 32 + lk * 8));
            #pragma unroll
            for (int mi = 0; mi < 2; ++mi) {
                f32x4 a = f32x4{0.f, 0.f, 0.f, 0.f};
                #pragma unroll
                for (int k = 0; k < KT; ++k)
                    a = mfma32(cwf[mi * KT + k], bfr[k], a);
                const int col = ct * 16 + l15, o0 = (w * 2 + mi) * 16 + lk * 4;
                const float z0 = fmaxf(a.x + cbv[mi].x, 0.f);
                const float z1 = fmaxf(a.y + cbv[mi].y, 0.f);
                const float z2 = fmaxf(a.z + cbv[mi].z, 0.f);
                const float z3 = fmaxf(a.w + cbv[mi].w, 0.f);
                const int off = swz<128>(col, o0);
                *(uint_t*)(Zs + off)     = pk2(z0, z1);
                *(uint_t*)(Zs + off + 2) = pk2(z2, z3);
            }
        }
        __syncthreads();

        // ---- phase B: kv GEMM -> Ks/Vs; LDS-write of prefetched y ----
        #pragma unroll
        for (int ct = 0; ct < 2; ++ct) {
            bf16x8 bfr[4];
            #pragma unroll
            for (int k = 0; k < 4; ++k)
                bfr[k] = *(const bf16x8*)(Zs + swz<128>(ct * 16 + l15, k * 32 + lk * 8));
            const int col = ct * 16 + l15;
            #pragma unroll
            for (int mi = 0; mi < 4; ++mi) {
                f32x4 a = f32x4{0.f, 0.f, 0.f, 0.f};
                #pragma unroll
                for (int k = 0; k < 4; ++k)
                    a = mfma32(kwf[mi * 4 + k], bfr[k], a);
                const int j0 = (w * 4 + mi) * 16 + lk * 4;
                const int h = j0 >> 6;
                const int d0 = (j0 & 63) >> 1;   // even
                *(uint_t*)(Ks + swz<128>(col, h * 32 + d0)) = pk2(a.x, a.z);
                const uint_t vv = pk2(a.y, a.w);
                Vs[swz<32>(h * 32 + d0,     col)] = (ushort_t)vv;
                Vs[swz<32>(h * 32 + d0 + 1, col)] = (ushort_t)(vv >> 16);
            }
        }
        if (cc < 7) write_y2<CIN>(Ys, yreg, tid);
        else if constexpr (NCIN != 0) write_y2<NCIN>(Ys, yreg, tid);
        __syncthreads();

        // ---- phase C: MFMA logits + softmax + MFMA PV (wave-local) ----
#if HAVE_MFMA16
        {
            const int pt = w >> 1, pr = w & 1;   // point in chunk, head-pair
            #pragma unroll
            for (int hh = 0; hh < 2; ++hh) {
                const int h = pr * 2 + hh;
                // QK^T: D[kk][*] = K[kk][d] x q[d]   (A row=kk=l15, k=d=lk*8+j)
                bf16x8 ka  = *(const bf16x8*)(Ks + swz<128>(pt * 16 + l15, h * 32 + lk * 8));
                bf16x8 qf  = *(const bf16x8*)(qs + swz<256>(cc * 2 + pt, qb + h * 32 + lk * 8));
                f32x4 zero = f32x4{0.f, 0.f, 0.f, 0.f};
                f32x4 sc = mfma32(ka, qf, zero);
                // lane holds S[kk = lk*4+reg] (cols duplicated across l15)
                float s0 = sc.x * SCALEf, s1 = sc.y * SCALEf;
                float s2 = sc.z * SCALEf, s3 = sc.w * SCALEf;
                float mx = fmaxf(fmaxf(s0, s1), fmaxf(s2, s3));
                mx = fmaxf(mx, __shfl_xor(mx, 16));
                mx = fmaxf(mx, __shfl_xor(mx, 32));
                float e0 = __expf(s0 - mx), e1 = __expf(s1 - mx);
                float e2 = __expf(s2 - mx), e3 = __expf(s3 - mx);
                float t = e0 + e1 + e2 + e3;
                t += __shfl_xor(t, 16);
                t += __shfl_xor(t, 32);
                const float r = 1.f / t;
                union { uint_t u[2]; bf16x4 v; } pf;
                pf.u[0] = pk2(e0 * r, e1 * r);
                pf.u[1] = pk2(e2 * r, e3 * r);
                // PV: D[d][*] = V[d][kk] x P[kk]  (A row=d=l15, k=kk=lk*4+j)
                #pragma unroll
                for (int dblk = 0; dblk < 2; ++dblk) {
                    bf16x4 va = *(const bf16x4*)(Vs + swz<32>(h * 32 + dblk * 16 + l15, pt * 16 + lk * 4));
                    f32x4 o = mfma16(va, pf.v, zero);
                    if (l15 == 0) {
                        uint2 ou;
                        ou.x = pk2(o.x, o.y);
                        ou.y = pk2(o.z, o.w);
                        *(uint2*)(aobuf + ((size_t)(b * Nn + n0 + cc * 2 + pt)) * 256
                                  + qb + h * 32 + dblk * 16 + lk * 4) = ou;
                    }
                }
            }
        }
#else
        {
            const int pt = w >> 1, pr = w & 1;
            float p = 0.f;
            if (lane < 32) {
                const int kk = lane & 15;
                const int h = pr * 2 + (lane >> 4);
                float s = 0.f;
                #pragma unroll
                for (int dc = 0; dc < 4; ++dc) {
                    bf16x8 q8 = *(const bf16x8*)(qs + swz<256>(cc * 2 + pt, qb + h * 32 + dc * 8));
                    bf16x8 k8 = *(const bf16x8*)(Ks + swz<128>(pt * 16 + kk, h * 32 + dc * 8));
                    #pragma unroll
                    for (int j = 0; j < 8; ++j)
                        s += b2f((ushort_t)q8[j]) * b2f((ushort_t)k8[j]);
                }
                s *= SCALEf;
                float mx = s;
                #pragma unroll
                for (int m = 1; m < 16; m <<= 1) mx = fmaxf(mx, __shfl_xor(mx, m));
                const float e = __expf(s - mx);
                float sum = e;
                #pragma unroll
                for (int m = 1; m < 16; m <<= 1) sum += __shfl_xor(sum, m);
                p = e / sum;
            }
            const int d = lane & 31, hh2 = lane >> 5;
            const int h2 = pr * 2 + hh2;
            const int row = h2 * 32 + d;
            bf16x8 va = *(const bf16x8*)(Vs + swz<32>(row, pt * 16));
            bf16x8 vb = *(const bf16x8*)(Vs + swz<32>(row, pt * 16 + 8));
            float o = 0.f;
            #pragma unroll
            for (int j = 0; j < 8; ++j) {
                o += __shfl(p, hh2 * 16 + j)     * b2f((ushort_t)va[j]);
                o += __shfl(p, hh2 * 16 + 8 + j) * b2f((ushort_t)vb[j]);
            }
            aobuf[((size_t)(b * Nn + n0 + cc * 2 + pt)) * 256 + qb + h2 * 32 + d] = (ushort_t)f2b(o);
        }
#endif
    }
}

// -------- fused attention kernel: inline Q GEMM + both branches --------
__global__ __launch_bounds__(256, 2) void k_attn(
    const float* __restrict__ x, const float* __restrict__ y0, const float* __restrict__ y1,
    const char* __restrict__ ws, ushort_t* __restrict__ aobuf) {

    __shared__ __align__(16) ushort_t qs[4096];   // [16 pt][256 ch] swz
    __shared__ __align__(16) ushort_t Ys[4096];   // [32 col][CIN] (X overlay in prologue)
    __shared__ __align__(16) ushort_t Zs[4096];   // [32 col][128 o]
    __shared__ __align__(16) ushort_t Ks[4096];   // [32 col][128 hd]
    __shared__ __align__(16) ushort_t Vs[4096];   // [128 hd][32 col]

    const int tid = threadIdx.x;
    const int b = blockIdx.x >> 9, n0 = (blockIdx.x & 511) << 4;
    const int w = tid >> 6, lane = tid & 63, l15 = lane & 15, lk = lane >> 4;
    float yreg[16];

    // ---- prologue: stage x in two 8-reg halves (cuts peak pressure) ----
    const int xn = tid & 15, cg = tid >> 4;
    #pragma unroll
    for (int hseg = 0; hseg < 2; ++hseg) {
        float xreg[8];
        #pragma unroll
        for (int i = 0; i < 8; ++i)
            xreg[i] = x[((size_t)(b * 256 + cg * 16 + hseg * 8 + i)) * Nn + n0 + xn];
        #pragma unroll
        for (int j = 0; j < 4; ++j)
            *(uint_t*)(Ys + swz<256>(xn, cg * 16 + hseg * 8 + 2 * j)) =
                pk2(xreg[2 * j], xreg[2 * j + 1]);
    }
    issue_y2<64>(y0, b, n0, yreg, tid);
    __syncthreads();

    // ---- Q GEMM: qs[pt][ch] = QW[ch][c] * X[c][pt] ----
    {
        const ushort_t* qwb = (const ushort_t*)(ws + WS_QW);
        #pragma unroll
        for (int mi = 0; mi < 4; ++mi) {
            f32x4 acc = f32x4{0.f, 0.f, 0.f, 0.f};
            #pragma unroll
            for (int k = 0; k < 8; ++k) {
                bf16x8 af = *(const bf16x8*)(qwb + ((w * 4 + mi) * 16 + l15) * 256 + k * 32 + lk * 8);
                bf16x8 bf = *(const bf16x8*)(Ys + swz<256>(l15, k * 32 + lk * 8));
                acc = mfma32(af, bf, acc);
            }
            const int ch0 = (w * 4 + mi) * 16 + lk * 4;
            uint2 u;
            u.x = pk2(acc.x, acc.y);
            u.y = pk2(acc.z, acc.w);
            *(uint2*)(qs + swz<256>(l15, ch0)) = u;
        }
    }
    __syncthreads();

    write_y2<64>(Ys, yreg, tid);   // X dead; stage branch0 chunk0
    __syncthreads();

    branch_run<64, 128>(tid, b, n0, y0, y1, ws, Ys, Zs, Ks, Vs, qs, aobuf, yreg);
    branch_run<128, 0> (tid, b, n0, y1, nullptr, ws, Ys, Zs, Ks, Vs, qs, aobuf, yreg);
}

// -------- proj GEMM + bias -> out[b][co][n] f32 --------
__global__ __launch_bounds__(256, 2) void k_proj(const char* __restrict__ ws,
                                                 const float* __restrict__ proj_b,
                                                 float* __restrict__ out) {
    __shared__ __align__(16) ushort_t At[64 * 256];
    const ushort_t* pwb = (const ushort_t*)(ws + WS_PW);
    const ushort_t* aobuf = (const ushort_t*)(ws + WS_AO);
    const int tid = threadIdx.x;
    const int b = blockIdx.x >> 7, n0 = (blockIdx.x & 127) * 64;

    {   // stage ao[n][ch] -> At[n][c] (bf16 pairs)
        const int cp = tid & 127, ng = tid >> 7;
        #pragma unroll
        for (int i = 0; i < 32; ++i) {
            const int n = ng + i * 2;
            const uint_t u = *(const uint_t*)(aobuf + ((size_t)(b * Nn + n0 + n)) * 256 + cp * 2);
            *(uint_t*)(At + swz<256>(n, cp * 2)) = u;
        }
    }
    __syncthreads();

    const int w = tid >> 6, lane = tid & 63, l15 = lane & 15, lk = lane >> 4;
    #pragma unroll
    for (int mi = 0; mi < 4; ++mi) {
        bf16x8 af[8];
        #pragma unroll
        for (int k = 0; k < 8; ++k)
            af[k] = *(const bf16x8*)(pwb + (w * 64 + mi * 16 + l15) * 256 + k * 32 + lk * 8);
        const int ch0 = w * 64 + mi * 16 + lk * 4;
        const float4 pbv = *(const float4*)(proj_b + ch0);
        #pragma unroll
        for (int ct = 0; ct < 4; ++ct) {
            f32x4 acc = f32x4{0.f, 0.f, 0.f, 0.f};
            #pragma unroll
            for (int k = 0; k < 8; ++k) {
                bf16x8 bf = *(const bf16x8*)(At + swz<256>(ct * 16 + l15, k * 32 + lk * 8));
                acc = mfma32(af[k], bf, acc);
            }
            const int nn = n0 + ct * 16 + l15;
            out[((size_t)(b * 256 + ch0 + 0)) * Nn + nn] = acc.x + pbv.x;
            out[((size_t)(b * 256 + ch0 + 1)) * Nn + nn] = acc.y + pbv.y;
            out[((size_t)(b * 256 + ch0 + 2)) * Nn + nn] = acc.z + pbv.z;
            out[((size_t)(b * 256 + ch0 + 3)) * Nn + nn] = acc.w + pbv.w;
        }
    }
}

extern "C" void kernel_launch(void* const* d_in, const int* in_sizes, int n_in,
                              void* d_out, int out_size, void* d_ws, size_t ws_size,
                              hipStream_t stream) {
    const float* x       = (const float*)d_in[0];
    const float* y0      = (const float*)d_in[1];
    const float* y1      = (const float*)d_in[2];
    const float* q_w     = (const float*)d_in[3];
    const float* conv0_w = (const float*)d_in[4];
    const float* bn0_g   = (const float*)d_in[5];
    const float* bn0_b   = (const float*)d_in[6];
    const float* bn0_m   = (const float*)d_in[7];
    const float* bn0_v   = (const float*)d_in[8];
    const float* kv0_w   = (const float*)d_in[9];
    const float* conv1_w = (const float*)d_in[10];
    const float* bn1_g   = (const float*)d_in[11];
    const float* bn1_b   = (const float*)d_in[12];
    const float* bn1_m   = (const float*)d_in[13];
    const float* bn1_v   = (const float*)d_in[14];
    const float* kv1_w   = (const float*)d_in[15];
    const float* proj_w  = (const float*)d_in[16];
    const float* proj_b  = (const float*)d_in[17];
    char* ws = (char*)d_ws;

    plsa_prep<<<256, 256, 0, stream>>>(q_w, conv0_w, bn0_g, bn0_b, bn0_m, bn0_v, kv0_w,
                                       conv1_w, bn1_g, bn1_b, bn1_m, bn1_v, kv1_w,
                                       proj_w, ws);
    k_attn<<<Bn * (Nn / 16), 256, 0, stream>>>(x, y0, y1, ws,
                                               (ushort_t*)(ws + WS_AO));
    k_proj<<<Bn * (Nn / 64), 256, 0, stream>>>(ws, proj_b, (float*)d_out);
}